// Round 13
// baseline (26.236 us; speedup 1.0000x reference)
//
#include <hip/hip_runtime.h>
#include <math.h>

#define DIM 1024
#define KK 7
#define DIL 2
#define BATCH 16384
#define NEG 0.01f
#define ROWS 8      // rows per block, grid = 2048 (= 8 blocks/CU exactly, no tail)
#define NBUF 3      // per-wave row slots (depth-2 prefetch + current)
#define DEPTH 2     // rows issued ahead
#define SLOT 320    // floats per slot: 256 main + halo region (windows read [0,268))

// Direct global->LDS DMA; no destination VGPR -> un-sinkable; vmcnt-tracked.
__device__ __forceinline__ void gload_lds16(const float* g, float* l) {
    __builtin_amdgcn_global_load_lds(
        (const __attribute__((address_space(1))) void*)g,
        (__attribute__((address_space(3))) void*)l, 16, 0, 0);
}
__device__ __forceinline__ void gload_lds4(const float* g, float* l) {
    __builtin_amdgcn_global_load_lds(
        (const __attribute__((address_space(1))) void*)g,
        (__attribute__((address_space(3))) void*)l, 4, 0, 0);
}

// ---------------------------------------------------------------------------
// R11 structure (barrier-free per-wave pipelines, counted vmcnt). Halo-traffic
// fix v2: R12's exec-predicated halo load corrupted LDS (global_load_lds dest
// is HW wave-uniform-base + lane*size; partial exec is NOT a clean partial
// write -> ledger rule: never predicate gload_lds). Instead ALL 64 lanes stay
// active and lanes >=12 load min(lane,11): same 64B cache line as lanes 0-11,
// so halo traffic drops 256B -> 64B per row/wave with R11's exact exec/count
// behavior. Junk lands in slot[268..320), never read. Wave 3 keeps the
// full-wave dummy-sink halo load so per-wave vmcnt stays symmetric; wait
// schedule {4,5,6,6,6,6,4,2} identical to the passing R11.
// ---------------------------------------------------------------------------
__global__ __launch_bounds__(256)
void cnn_flow_fused(const float* __restrict__ x,
                    const float* __restrict__ wgt,
                    const float* __restrict__ bias,
                    const float* __restrict__ lmbd,
                    float* __restrict__ out,
                    float* __restrict__ logdet) {
    const int t    = threadIdx.x;
    const int wv   = t >> 6;
    const int lane = t & 63;
    const int base = t << 2;                  // global feature = wv*256+lane*4
    const int row0 = blockIdx.x * ROWS;

    __shared__ float sx[4 * NBUF * SLOT];     // 15360 B staging
    __shared__ float red[ROWS][4];            // per-row wave partials
    __shared__ float dummy[64];               // sink for wave 3's halo loads

    // wave 3: zero the read-halo region of its own slots once (never gloaded)
    if (wv == 3 && lane < 16) {
#pragma unroll
        for (int s = 0; s < NBUF; ++s)
            sx[(3 * NBUF + s) * SLOT + 256 + lane] = 0.0f;
    }

    const float* growbase = x + (size_t)row0 * DIM;
    const float* gmain = growbase + (wv << 8) + (lane << 2);   // 16B/lane
    // halo source: lanes 0..11 fetch the 12 needed floats; lanes 12..63 clamp
    // to float 11 -> same 64B line, no extra traffic, full exec mask.
    const int hl = (lane < 12) ? lane : 11;
    const float* ghalo = growbase + ((wv < 3) ? (wv << 8) + 256 : 0) + hl;

    auto issue_row = [&](int r) {
        float* slot = sx + (wv * NBUF + (r % NBUF)) * SLOT;
        gload_lds16(gmain + r * DIM, slot + (lane << 2));
        gload_lds4(ghalo + r * DIM, ((wv < 3) ? slot + 256 : dummy) + lane);
    };

    // prologue: rows 0,1 in flight
    issue_row(0);
    issue_row(1);

    // scalar params + per-feature tables: computed while prologue loads fly
    float w[KK];
#pragma unroll
    for (int k = 0; k < KK; ++k) w[k] = wgt[k];
    const float w0 = w[0];
    const float bs = bias[0];

    float sc[4], lp[4], ln[4];
    {
        float4 lm = *reinterpret_cast<const float4*>(lmbd + base);
        float lms[4] = {lm.x, lm.y, lm.z, lm.w};
        const float inv = (w0 != 0.0f) ? (-1.0f / w0) : 0.0f;
#pragma unroll
        for (int i = 0; i < 4; ++i) {
            float l  = lms[i];
            float sp = fmaxf(l, 0.0f) + log1pf(expf(-fabsf(l)));  // softplus
            float scale;
            if (w0 == 0.0f)      scale = l;
            else if (w0 > 0.0f)  scale = inv + sp;
            else                 scale = inv - sp;
            sc[i] = scale;
            lp[i] = logf(fabsf(fmaf(scale,       w0, 1.0f)));   // act_grad=1
            ln[i] = logf(fabsf(fmaf(NEG * scale, w0, 1.0f)));   // act_grad=NEG
        }
    }

#pragma unroll
    for (int r = 0; r < ROWS; ++r) {
        if (r + DEPTH < ROWS) issue_row(r + DEPTH);

        // counted per-wave wait: row r's 2 load instrs retired, newer loads +
        // stores stay in flight. Position-derived: {4,5,6,6,6,6,4,2}.
        if      (r == 0) asm volatile("s_waitcnt vmcnt(4)" ::: "memory");
        else if (r == 1) asm volatile("s_waitcnt vmcnt(5)" ::: "memory");
        else if (r == 6) asm volatile("s_waitcnt vmcnt(4)" ::: "memory");
        else if (r == 7) asm volatile("s_waitcnt vmcnt(2)" ::: "memory");
        else             asm volatile("s_waitcnt vmcnt(6)" ::: "memory");

        const float* srow = sx + (wv * NBUF + (r % NBUF)) * SLOT + (lane << 2);
        float xv[16];
#pragma unroll
        for (int j = 0; j < 4; ++j) {         // 4x ds_read_b128, wave-private
            float4 v = *reinterpret_cast<const float4*>(srow + 4 * j);
            xv[4 * j + 0] = v.x; xv[4 * j + 1] = v.y;
            xv[4 * j + 2] = v.z; xv[4 * j + 3] = v.w;
        }

        float ld_acc = 0.0f;
        float o[4];
#pragma unroll
        for (int i = 0; i < 4; ++i) {
            float conv = bs;
#pragma unroll
            for (int kk = 0; kk < KK; ++kk)
                conv = fmaf(xv[i + DIL * kk], w[kk], conv);
            bool pos  = (conv >= 0.0f);
            float act = pos ? conv : NEG * conv;
            o[i]      = fmaf(act, sc[i], xv[i]);
            ld_acc   += pos ? lp[i] : ln[i];
        }
        *reinterpret_cast<float4*>(out + (size_t)(row0 + r) * DIM + base) =
            make_float4(o[0], o[1], o[2], o[3]);

        // wave shuffle reduce (hidden); park per-wave partial, fire-and-forget
#pragma unroll
        for (int off = 32; off > 0; off >>= 1)
            ld_acc += __shfl_down(ld_acc, off, 64);
        if (lane == 0) red[r][wv] = ld_acc;
    }

    __syncthreads();                          // only barrier in the kernel
    if (t < ROWS)
        logdet[row0 + t] = (red[t][0] + red[t][1]) + (red[t][2] + red[t][3]);
}

extern "C" void kernel_launch(void* const* d_in, const int* in_sizes, int n_in,
                              void* d_out, int out_size, void* d_ws, size_t ws_size,
                              hipStream_t stream) {
    const float* x    = (const float*)d_in[0];
    const float* wgt  = (const float*)d_in[1];
    const float* bias = (const float*)d_in[2];
    const float* lmbd = (const float*)d_in[3];
    float* out    = (float*)d_out;                    // (BATCH, DIM)
    float* logdet = out + (size_t)BATCH * DIM;        // (BATCH,)

    cnn_flow_fused<<<BATCH / ROWS, 256, 0, stream>>>(x, wgt, bias, lmbd, out, logdet);
}